// Round 1
// baseline (2233.995 us; speedup 1.0000x reference)
//
#include <hip/hip_runtime.h>

#define N_NODES 100000
#define N_EDGES 1600000
#define D_IN    256
#define D_HID   64
#define D_OUT   40
#define PROP_N  16

// ---------------------------------------------------------------------------
// Kernel 1: CSR row_ptr from sorted edge_row via binary search (lower_bound).
// ---------------------------------------------------------------------------
__global__ __launch_bounds__(256) void build_rowptr(const int* __restrict__ erow,
                                                    int* __restrict__ rp) {
    int r = blockIdx.x * blockDim.x + threadIdx.x;
    if (r > N_NODES) return;
    int lo = 0, hi = N_EDGES;
    while (lo < hi) {
        int mid = (lo + hi) >> 1;
        if (erow[mid] < r) lo = mid + 1; else hi = mid;
    }
    rp[r] = lo;
}

// ---------------------------------------------------------------------------
// Kernel 2: h = x @ W1 + b1 ; Y0 = h ; src = 0.5 * diag * h
// Block = 256 threads, 16 nodes/block. Thread (d = tid&63, ng = tid>>6)
// computes dim d for 4 nodes. W1 (64 KB) staged in LDS; x rows are
// wave-uniform loads (broadcast / scalarizable).
// ---------------------------------------------------------------------------
__global__ __launch_bounds__(256) void mlp1(const float* __restrict__ x,
                                            const float* __restrict__ W1,
                                            const float* __restrict__ b1,
                                            const float* __restrict__ diag,
                                            float* __restrict__ Y0,
                                            float* __restrict__ src) {
    __shared__ float W1s[D_IN * D_HID];  // 64 KB
    int tid = threadIdx.x;

    // stage W1: 16384 floats = 4096 float4, 256 threads -> 16 float4 each
    {
        const float4* W1v  = (const float4*)W1;
        float4*       W1sv = (float4*)W1s;
        #pragma unroll
        for (int i = 0; i < 16; ++i)
            W1sv[tid + 256 * i] = W1v[tid + 256 * i];
    }
    __syncthreads();

    const int d     = tid & 63;
    const int ng    = tid >> 6;                    // 0..3
    const int nbase = blockIdx.x * 16 + ng * 4;    // 4 nodes per thread

    float bias = b1[d];
    float acc0 = bias, acc1 = bias, acc2 = bias, acc3 = bias;

    const float4* x4 = (const float4*)x;           // row n starts at n*64 float4s
    const size_t r0 = (size_t)(nbase + 0) * 64;
    const size_t r1 = (size_t)(nbase + 1) * 64;
    const size_t r2 = (size_t)(nbase + 2) * 64;
    const size_t r3 = (size_t)(nbase + 3) * 64;

    #pragma unroll 4
    for (int k4 = 0; k4 < 64; ++k4) {
        float4 xa = x4[r0 + k4];
        float4 xb = x4[r1 + k4];
        float4 xc = x4[r2 + k4];
        float4 xd = x4[r3 + k4];
        int k = k4 * 4;
        float w0 = W1s[(k + 0) * 64 + d];
        float w1 = W1s[(k + 1) * 64 + d];
        float w2 = W1s[(k + 2) * 64 + d];
        float w3 = W1s[(k + 3) * 64 + d];
        acc0 = fmaf(xa.x, w0, acc0); acc0 = fmaf(xa.y, w1, acc0);
        acc0 = fmaf(xa.z, w2, acc0); acc0 = fmaf(xa.w, w3, acc0);
        acc1 = fmaf(xb.x, w0, acc1); acc1 = fmaf(xb.y, w1, acc1);
        acc1 = fmaf(xb.z, w2, acc1); acc1 = fmaf(xb.w, w3, acc1);
        acc2 = fmaf(xc.x, w0, acc2); acc2 = fmaf(xc.y, w1, acc2);
        acc2 = fmaf(xc.z, w2, acc2); acc2 = fmaf(xc.w, w3, acc2);
        acc3 = fmaf(xd.x, w0, acc3); acc3 = fmaf(xd.y, w1, acc3);
        acc3 = fmaf(xd.z, w2, acc3); acc3 = fmaf(xd.w, w3, acc3);
    }

    float dg0 = diag[nbase + 0], dg1 = diag[nbase + 1];
    float dg2 = diag[nbase + 2], dg3 = diag[nbase + 3];
    Y0[(size_t)(nbase + 0) * 64 + d] = acc0;
    Y0[(size_t)(nbase + 1) * 64 + d] = acc1;
    Y0[(size_t)(nbase + 2) * 64 + d] = acc2;
    Y0[(size_t)(nbase + 3) * 64 + d] = acc3;
    src[(size_t)(nbase + 0) * 64 + d] = 0.5f * dg0 * acc0;
    src[(size_t)(nbase + 1) * 64 + d] = 0.5f * dg1 * acc1;
    src[(size_t)(nbase + 2) * 64 + d] = 0.5f * dg2 * acc2;
    src[(size_t)(nbase + 3) * 64 + d] = 0.5f * dg3 * acc3;
}

// ---------------------------------------------------------------------------
// Kernel 3: one propagation step. One wave per row, lane = feature dim.
// Yout[r,:] = 0.5*Yin[r,:] + 0.5 * sum_e val[e]*Yin[col[e],:] + src[r,:]
// ---------------------------------------------------------------------------
__global__ __launch_bounds__(256) void prop_step(const float* __restrict__ Yin,
                                                 const float* __restrict__ src,
                                                 float* __restrict__ Yout,
                                                 const int* __restrict__ rp,
                                                 const int* __restrict__ ecol,
                                                 const float* __restrict__ evalv) {
    int w    = blockIdx.x * (blockDim.x >> 6) + (threadIdx.x >> 6);
    int lane = threadIdx.x & 63;
    if (w >= N_NODES) return;

    // row bounds are wave-uniform; force into SGPRs so edge loads scalarize
    int e0 = __builtin_amdgcn_readfirstlane(rp[w]);
    int e1 = __builtin_amdgcn_readfirstlane(rp[w + 1]);

    float acc = 0.0f;
    for (int e = e0; e < e1; ++e) {
        int   c = ecol[e];
        float v = evalv[e];
        acc = fmaf(v, Yin[(size_t)c * 64 + lane], acc);
    }

    size_t idx = (size_t)w * 64 + lane;
    Yout[idx] = fmaf(0.5f, Yin[idx], fmaf(0.5f, acc, src[idx]));
}

// ---------------------------------------------------------------------------
// Kernel 4: out = relu(Y) @ W2 + b2.  One node per thread, 40 accumulators.
// ---------------------------------------------------------------------------
__global__ __launch_bounds__(256) void mlp2(const float* __restrict__ Y,
                                            const float* __restrict__ W2,
                                            const float* __restrict__ b2,
                                            float* __restrict__ out) {
    __shared__ float W2s[D_HID * D_OUT];  // 10.2 KB
    __shared__ float b2s[D_OUT];
    int tid = threadIdx.x;
    for (int i = tid; i < D_HID * D_OUT; i += 256) W2s[i] = W2[i];
    if (tid < D_OUT) b2s[tid] = b2[tid];
    __syncthreads();

    int n = blockIdx.x * 256 + tid;
    if (n >= N_NODES) return;

    float acc[D_OUT];
    #pragma unroll
    for (int o = 0; o < D_OUT; ++o) acc[o] = b2s[o];

    const float4* Y4 = (const float4*)(Y + (size_t)n * 64);
    #pragma unroll 4
    for (int k4 = 0; k4 < 16; ++k4) {
        float4 y = Y4[k4];
        float ys[4];
        ys[0] = fmaxf(y.x, 0.0f); ys[1] = fmaxf(y.y, 0.0f);
        ys[2] = fmaxf(y.z, 0.0f); ys[3] = fmaxf(y.w, 0.0f);
        #pragma unroll
        for (int j = 0; j < 4; ++j) {
            int k = k4 * 4 + j;
            #pragma unroll
            for (int o = 0; o < D_OUT; ++o)
                acc[o] = fmaf(ys[j], W2s[k * D_OUT + o], acc[o]);
        }
    }

    float4* o4 = (float4*)(out + (size_t)n * D_OUT);  // 160 B row, 16B aligned
    #pragma unroll
    for (int q = 0; q < 10; ++q)
        o4[q] = make_float4(acc[4 * q], acc[4 * q + 1], acc[4 * q + 2], acc[4 * q + 3]);
}

// ---------------------------------------------------------------------------
extern "C" void kernel_launch(void* const* d_in, const int* in_sizes, int n_in,
                              void* d_out, int out_size, void* d_ws, size_t ws_size,
                              hipStream_t stream) {
    const float* x     = (const float*)d_in[0];
    const int*   erow  = (const int*)  d_in[1];
    const int*   ecol  = (const int*)  d_in[2];
    const float* evalv = (const float*)d_in[3];
    const float* diag  = (const float*)d_in[4];
    const float* W1    = (const float*)d_in[5];
    const float* b1    = (const float*)d_in[6];
    const float* W2    = (const float*)d_in[7];
    const float* b2    = (const float*)d_in[8];
    float* out = (float*)d_out;

    // workspace layout: Y0 | Y1 | src | row_ptr   (~77 MB)
    float* Y0  = (float*)d_ws;
    float* Y1  = Y0 + (size_t)N_NODES * D_HID;
    float* src = Y1 + (size_t)N_NODES * D_HID;
    int*   rp  = (int*)(src + (size_t)N_NODES * D_HID);

    build_rowptr<<<(N_NODES + 1 + 255) / 256, 256, 0, stream>>>(erow, rp);
    mlp1<<<N_NODES / 16, 256, 0, stream>>>(x, W1, b1, diag, Y0, src);

    float* bufs[2] = {Y0, Y1};
    for (int i = 0; i < PROP_N; ++i) {
        prop_step<<<N_NODES / 4, 256, 0, stream>>>(bufs[i & 1], src, bufs[(i + 1) & 1],
                                                   rp, ecol, evalv);
    }
    // PROP_N even -> final result in Y0
    mlp2<<<(N_NODES + 255) / 256, 256, 0, stream>>>(Y0, W2, b2, out);
}

// Round 2
// 1316.190 us; speedup vs baseline: 1.6973x; 1.6973x over previous
//
#include <hip/hip_runtime.h>

#define N_NODES 100000
#define N_EDGES 1600000
#define D_IN    256
#define D_HID   64
#define D_OUT   40
#define PROP_N  16

// ---------------------------------------------------------------------------
// Kernel 1: CSR row_ptr from sorted edge_row via binary search (lower_bound).
// ---------------------------------------------------------------------------
__global__ __launch_bounds__(256) void build_rowptr(const int* __restrict__ erow,
                                                    int* __restrict__ rp) {
    int r = blockIdx.x * blockDim.x + threadIdx.x;
    if (r > N_NODES) return;
    int lo = 0, hi = N_EDGES;
    while (lo < hi) {
        int mid = (lo + hi) >> 1;
        if (erow[mid] < r) lo = mid + 1; else hi = mid;
    }
    rp[r] = lo;
}

// ---------------------------------------------------------------------------
// Kernel 2: h = x @ W1 + b1 ; Y0 = h ; src = 0.5 * diag * h
// Block = 256 threads, 32 nodes/block. LDS holds the x tile (32 KB ->
// 5 blocks/CU). Thread (dp = (tid&31)*2, ng = tid>>5) computes dims
// {dp,dp+1} for nodes ng*4..ng*4+3. x comes from LDS broadcast reads
// (all lanes in a half-wave read the same address -> conflict-free);
// W1 rows are streamed coalesced and reused by all 4 waves (L1/L2 hits).
// ---------------------------------------------------------------------------
__global__ __launch_bounds__(256) void mlp1(const float* __restrict__ x,
                                            const float* __restrict__ W1,
                                            const float* __restrict__ b1,
                                            const float* __restrict__ diag,
                                            float* __restrict__ Y0,
                                            float* __restrict__ src) {
    __shared__ float xs[32 * D_IN];  // 32 KB
    const int tid   = threadIdx.x;
    const int nbase = blockIdx.x * 32;

    // stage x tile: 32 rows * 256 floats = 2048 float4; 8 per thread, coalesced
    {
        const float4* xv  = (const float4*)(x + (size_t)nbase * D_IN);
        float4*       xsv = (float4*)xs;
        #pragma unroll
        for (int i = 0; i < 8; ++i)
            xsv[tid + 256 * i] = xv[tid + 256 * i];
    }
    __syncthreads();

    const int dp = (tid & 31) * 2;   // dim pair
    const int ng = tid >> 5;         // node group 0..7 (4 nodes each)

    const float bx = b1[dp], by = b1[dp + 1];
    float a[4][2];
    #pragma unroll
    for (int i = 0; i < 4; ++i) { a[i][0] = bx; a[i][1] = by; }

    const float* xrow = xs + (size_t)(ng * 4) * D_IN;

    for (int k4 = 0; k4 < 64; ++k4) {
        const int k = k4 * 4;
        float2 w0 = *(const float2*)&W1[(k + 0) * 64 + dp];
        float2 w1 = *(const float2*)&W1[(k + 1) * 64 + dp];
        float2 w2 = *(const float2*)&W1[(k + 2) * 64 + dp];
        float2 w3 = *(const float2*)&W1[(k + 3) * 64 + dp];
        #pragma unroll
        for (int i = 0; i < 4; ++i) {
            float4 xq = *(const float4*)&xrow[i * D_IN + k];
            a[i][0] = fmaf(xq.x, w0.x, a[i][0]); a[i][1] = fmaf(xq.x, w0.y, a[i][1]);
            a[i][0] = fmaf(xq.y, w1.x, a[i][0]); a[i][1] = fmaf(xq.y, w1.y, a[i][1]);
            a[i][0] = fmaf(xq.z, w2.x, a[i][0]); a[i][1] = fmaf(xq.z, w2.y, a[i][1]);
            a[i][0] = fmaf(xq.w, w3.x, a[i][0]); a[i][1] = fmaf(xq.w, w3.y, a[i][1]);
        }
    }

    #pragma unroll
    for (int i = 0; i < 4; ++i) {
        const int n = nbase + ng * 4 + i;
        const float dg = diag[n];
        float2 h  = make_float2(a[i][0], a[i][1]);
        float2 sc = make_float2(0.5f * dg * h.x, 0.5f * dg * h.y);
        *(float2*)&Y0[(size_t)n * 64 + dp]  = h;
        *(float2*)&src[(size_t)n * 64 + dp] = sc;
    }
}

// ---------------------------------------------------------------------------
// Kernel 3: one propagation step. One wave per row, lane = feature dim.
// Unroll-by-4 with independent accumulators: 4 gathers in flight per wave.
// Yout[r,:] = 0.5*Yin[r,:] + 0.5 * sum_e val[e]*Yin[col[e],:] + src[r,:]
// ---------------------------------------------------------------------------
__global__ __launch_bounds__(256) void prop_step(const float* __restrict__ Yin,
                                                 const float* __restrict__ src,
                                                 float* __restrict__ Yout,
                                                 const int* __restrict__ rp,
                                                 const int* __restrict__ ecol,
                                                 const float* __restrict__ evalv) {
    int w    = blockIdx.x * (blockDim.x >> 6) + (threadIdx.x >> 6);
    int lane = threadIdx.x & 63;
    if (w >= N_NODES) return;

    // row bounds are wave-uniform; force into SGPRs so edge loads scalarize
    int e0 = __builtin_amdgcn_readfirstlane(rp[w]);
    int e1 = __builtin_amdgcn_readfirstlane(rp[w + 1]);

    const size_t idx = (size_t)w * 64 + lane;
    float yself = Yin[idx];   // hoisted: overlaps with gather loop
    float sv    = src[idx];

    float a0 = 0.0f, a1 = 0.0f, a2 = 0.0f, a3 = 0.0f;
    int e = e0;
    for (; e + 4 <= e1; e += 4) {
        int   c0 = ecol[e + 0], c1 = ecol[e + 1], c2 = ecol[e + 2], c3 = ecol[e + 3];
        float v0 = evalv[e + 0], v1 = evalv[e + 1], v2 = evalv[e + 2], v3 = evalv[e + 3];
        float y0 = Yin[(size_t)c0 * 64 + lane];
        float y1 = Yin[(size_t)c1 * 64 + lane];
        float y2 = Yin[(size_t)c2 * 64 + lane];
        float y3 = Yin[(size_t)c3 * 64 + lane];
        a0 = fmaf(v0, y0, a0);
        a1 = fmaf(v1, y1, a1);
        a2 = fmaf(v2, y2, a2);
        a3 = fmaf(v3, y3, a3);
    }
    for (; e < e1; ++e)
        a0 = fmaf(evalv[e], Yin[(size_t)ecol[e] * 64 + lane], a0);

    float acc = (a0 + a1) + (a2 + a3);
    Yout[idx] = fmaf(0.5f, yself, fmaf(0.5f, acc, sv));
}

// ---------------------------------------------------------------------------
// Kernel 4: out = relu(Y) @ W2 + b2.  One node per thread, 40 accumulators.
// ---------------------------------------------------------------------------
__global__ __launch_bounds__(256) void mlp2(const float* __restrict__ Y,
                                            const float* __restrict__ W2,
                                            const float* __restrict__ b2,
                                            float* __restrict__ out) {
    __shared__ float W2s[D_HID * D_OUT];  // 10.2 KB
    __shared__ float b2s[D_OUT];
    int tid = threadIdx.x;
    for (int i = tid; i < D_HID * D_OUT; i += 256) W2s[i] = W2[i];
    if (tid < D_OUT) b2s[tid] = b2[tid];
    __syncthreads();

    int n = blockIdx.x * 256 + tid;
    if (n >= N_NODES) return;

    float acc[D_OUT];
    #pragma unroll
    for (int o = 0; o < D_OUT; ++o) acc[o] = b2s[o];

    const float4* Y4 = (const float4*)(Y + (size_t)n * 64);
    #pragma unroll 4
    for (int k4 = 0; k4 < 16; ++k4) {
        float4 y = Y4[k4];
        float ys[4];
        ys[0] = fmaxf(y.x, 0.0f); ys[1] = fmaxf(y.y, 0.0f);
        ys[2] = fmaxf(y.z, 0.0f); ys[3] = fmaxf(y.w, 0.0f);
        #pragma unroll
        for (int j = 0; j < 4; ++j) {
            int k = k4 * 4 + j;
            #pragma unroll
            for (int o = 0; o < D_OUT; ++o)
                acc[o] = fmaf(ys[j], W2s[k * D_OUT + o], acc[o]);
        }
    }

    float4* o4 = (float4*)(out + (size_t)n * D_OUT);  // 160 B row, 16B aligned
    #pragma unroll
    for (int q = 0; q < 10; ++q)
        o4[q] = make_float4(acc[4 * q], acc[4 * q + 1], acc[4 * q + 2], acc[4 * q + 3]);
}

// ---------------------------------------------------------------------------
extern "C" void kernel_launch(void* const* d_in, const int* in_sizes, int n_in,
                              void* d_out, int out_size, void* d_ws, size_t ws_size,
                              hipStream_t stream) {
    const float* x     = (const float*)d_in[0];
    const int*   erow  = (const int*)  d_in[1];
    const int*   ecol  = (const int*)  d_in[2];
    const float* evalv = (const float*)d_in[3];
    const float* diag  = (const float*)d_in[4];
    const float* W1    = (const float*)d_in[5];
    const float* b1    = (const float*)d_in[6];
    const float* W2    = (const float*)d_in[7];
    const float* b2    = (const float*)d_in[8];
    float* out = (float*)d_out;

    // workspace layout: Y0 | Y1 | src | row_ptr
    float* Y0  = (float*)d_ws;
    float* Y1  = Y0 + (size_t)N_NODES * D_HID;
    float* src = Y1 + (size_t)N_NODES * D_HID;
    int*   rp  = (int*)(src + (size_t)N_NODES * D_HID);

    build_rowptr<<<(N_NODES + 1 + 255) / 256, 256, 0, stream>>>(erow, rp);
    mlp1<<<N_NODES / 32, 256, 0, stream>>>(x, W1, b1, diag, Y0, src);

    float* bufs[2] = {Y0, Y1};
    for (int i = 0; i < PROP_N; ++i) {
        prop_step<<<N_NODES / 4, 256, 0, stream>>>(bufs[i & 1], src, bufs[(i + 1) & 1],
                                                   rp, ecol, evalv);
    }
    // PROP_N even -> final result in Y0
    mlp2<<<(N_NODES + 255) / 256, 256, 0, stream>>>(Y0, W2, b2, out);
}

// Round 3
// 1023.789 us; speedup vs baseline: 2.1821x; 1.2856x over previous
//
#include <hip/hip_runtime.h>

#define N_NODES 100000
#define N_EDGES 1600000
#define D_IN    256
#define D_HID   64
#define D_OUT   40
#define PROP_N  16

// ---- bf16 helpers ---------------------------------------------------------
__device__ __forceinline__ unsigned short f32_to_bf16(float f) {
    unsigned int u = __float_as_uint(f);
    unsigned int r = (u + 0x7fffu + ((u >> 16) & 1u)) >> 16;   // RNE
    return (unsigned short)r;
}
__device__ __forceinline__ float bf16_to_f32(unsigned short h) {
    return __uint_as_float(((unsigned int)h) << 16);
}

// ---------------------------------------------------------------------------
// Kernel 1: CSR row_ptr from sorted edge_row via binary search (lower_bound).
// ---------------------------------------------------------------------------
__global__ __launch_bounds__(256) void build_rowptr(const int* __restrict__ erow,
                                                    int* __restrict__ rp) {
    int r = blockIdx.x * blockDim.x + threadIdx.x;
    if (r > N_NODES) return;
    int lo = 0, hi = N_EDGES;
    while (lo < hi) {
        int mid = (lo + hi) >> 1;
        if (erow[mid] < r) lo = mid + 1; else hi = mid;
    }
    rp[r] = lo;
}

// ---------------------------------------------------------------------------
// Kernel 1b: pack (col, val) into int2 so the edge loop does one 8B load/edge.
// ---------------------------------------------------------------------------
__global__ __launch_bounds__(256) void pack_edges(const int* __restrict__ ecol,
                                                  const float* __restrict__ evalv,
                                                  int2* __restrict__ ep) {
    int i = blockIdx.x * blockDim.x + threadIdx.x;
    if (i >= N_EDGES) return;
    ep[i] = make_int2(ecol[i], __float_as_int(evalv[i]));
}

// ---------------------------------------------------------------------------
// Kernel 2: h = x @ W1 + b1 ; Y0f = h ; Y0b = bf16(h) ; src = 0.5 * diag * h
// ---------------------------------------------------------------------------
__global__ __launch_bounds__(256) void mlp1(const float* __restrict__ x,
                                            const float* __restrict__ W1,
                                            const float* __restrict__ b1,
                                            const float* __restrict__ diag,
                                            float* __restrict__ Y0f,
                                            unsigned short* __restrict__ Y0b,
                                            float* __restrict__ src) {
    __shared__ float xs[32 * D_IN];  // 32 KB
    const int tid   = threadIdx.x;
    const int nbase = blockIdx.x * 32;

    {
        const float4* xv  = (const float4*)(x + (size_t)nbase * D_IN);
        float4*       xsv = (float4*)xs;
        #pragma unroll
        for (int i = 0; i < 8; ++i)
            xsv[tid + 256 * i] = xv[tid + 256 * i];
    }
    __syncthreads();

    const int dp = (tid & 31) * 2;   // dim pair
    const int ng = tid >> 5;         // node group 0..7 (4 nodes each)

    const float bx = b1[dp], by = b1[dp + 1];
    float a[4][2];
    #pragma unroll
    for (int i = 0; i < 4; ++i) { a[i][0] = bx; a[i][1] = by; }

    const float* xrow = xs + (size_t)(ng * 4) * D_IN;

    for (int k4 = 0; k4 < 64; ++k4) {
        const int k = k4 * 4;
        float2 w0 = *(const float2*)&W1[(k + 0) * 64 + dp];
        float2 w1 = *(const float2*)&W1[(k + 1) * 64 + dp];
        float2 w2 = *(const float2*)&W1[(k + 2) * 64 + dp];
        float2 w3 = *(const float2*)&W1[(k + 3) * 64 + dp];
        #pragma unroll
        for (int i = 0; i < 4; ++i) {
            float4 xq = *(const float4*)&xrow[i * D_IN + k];
            a[i][0] = fmaf(xq.x, w0.x, a[i][0]); a[i][1] = fmaf(xq.x, w0.y, a[i][1]);
            a[i][0] = fmaf(xq.y, w1.x, a[i][0]); a[i][1] = fmaf(xq.y, w1.y, a[i][1]);
            a[i][0] = fmaf(xq.z, w2.x, a[i][0]); a[i][1] = fmaf(xq.z, w2.y, a[i][1]);
            a[i][0] = fmaf(xq.w, w3.x, a[i][0]); a[i][1] = fmaf(xq.w, w3.y, a[i][1]);
        }
    }

    #pragma unroll
    for (int i = 0; i < 4; ++i) {
        const int n = nbase + ng * 4 + i;
        const float dg = diag[n];
        float2 h  = make_float2(a[i][0], a[i][1]);
        float2 sc = make_float2(0.5f * dg * h.x, 0.5f * dg * h.y);
        *(float2*)&Y0f[(size_t)n * 64 + dp]  = h;
        *(float2*)&src[(size_t)n * 64 + dp]  = sc;
        unsigned int hb = (unsigned int)f32_to_bf16(h.x) |
                          ((unsigned int)f32_to_bf16(h.y) << 16);
        *(unsigned int*)&Y0b[(size_t)n * 64 + dp] = hb;
    }
}

// ---------------------------------------------------------------------------
// Kernel 3: one propagation step. One wave per row, lane = feature dim.
// Gathers read the bf16 copy (128 B/row); self-term + src stay fp32 so
// quantization only enters via the 0.5*A path (error gain ~1x ulp).
// 8-wide unroll: 8 gathers + 8 edge loads in flight per wave.
// ---------------------------------------------------------------------------
__global__ __launch_bounds__(256) void prop_step(const float* __restrict__ Yf,
                                                 const unsigned short* __restrict__ Yb,
                                                 const float* __restrict__ src,
                                                 float* __restrict__ Yof,
                                                 unsigned short* __restrict__ Yob,
                                                 const int* __restrict__ rp,
                                                 const int2* __restrict__ ep) {
    int w    = blockIdx.x * (blockDim.x >> 6) + (threadIdx.x >> 6);
    int lane = threadIdx.x & 63;
    if (w >= N_NODES) return;

    int e0 = __builtin_amdgcn_readfirstlane(rp[w]);
    int e1 = __builtin_amdgcn_readfirstlane(rp[w + 1]);

    const size_t idx = (size_t)w * 64 + lane;
    float yself = Yf[idx];
    float sv    = src[idx];

    float a0 = 0.f, a1 = 0.f, a2 = 0.f, a3 = 0.f;
    float a4 = 0.f, a5 = 0.f, a6 = 0.f, a7 = 0.f;
    int e = e0;
    for (; e + 8 <= e1; e += 8) {
        int2 p0 = ep[e + 0], p1 = ep[e + 1], p2 = ep[e + 2], p3 = ep[e + 3];
        int2 p4 = ep[e + 4], p5 = ep[e + 5], p6 = ep[e + 6], p7 = ep[e + 7];
        float y0 = bf16_to_f32(Yb[(size_t)p0.x * 64 + lane]);
        float y1 = bf16_to_f32(Yb[(size_t)p1.x * 64 + lane]);
        float y2 = bf16_to_f32(Yb[(size_t)p2.x * 64 + lane]);
        float y3 = bf16_to_f32(Yb[(size_t)p3.x * 64 + lane]);
        float y4 = bf16_to_f32(Yb[(size_t)p4.x * 64 + lane]);
        float y5 = bf16_to_f32(Yb[(size_t)p5.x * 64 + lane]);
        float y6 = bf16_to_f32(Yb[(size_t)p6.x * 64 + lane]);
        float y7 = bf16_to_f32(Yb[(size_t)p7.x * 64 + lane]);
        a0 = fmaf(__int_as_float(p0.y), y0, a0);
        a1 = fmaf(__int_as_float(p1.y), y1, a1);
        a2 = fmaf(__int_as_float(p2.y), y2, a2);
        a3 = fmaf(__int_as_float(p3.y), y3, a3);
        a4 = fmaf(__int_as_float(p4.y), y4, a4);
        a5 = fmaf(__int_as_float(p5.y), y5, a5);
        a6 = fmaf(__int_as_float(p6.y), y6, a6);
        a7 = fmaf(__int_as_float(p7.y), y7, a7);
    }
    if (e + 4 <= e1) {
        int2 p0 = ep[e + 0], p1 = ep[e + 1], p2 = ep[e + 2], p3 = ep[e + 3];
        float y0 = bf16_to_f32(Yb[(size_t)p0.x * 64 + lane]);
        float y1 = bf16_to_f32(Yb[(size_t)p1.x * 64 + lane]);
        float y2 = bf16_to_f32(Yb[(size_t)p2.x * 64 + lane]);
        float y3 = bf16_to_f32(Yb[(size_t)p3.x * 64 + lane]);
        a0 = fmaf(__int_as_float(p0.y), y0, a0);
        a1 = fmaf(__int_as_float(p1.y), y1, a1);
        a2 = fmaf(__int_as_float(p2.y), y2, a2);
        a3 = fmaf(__int_as_float(p3.y), y3, a3);
        e += 4;
    }
    for (; e < e1; ++e) {
        int2 p = ep[e];
        a0 = fmaf(__int_as_float(p.y),
                  bf16_to_f32(Yb[(size_t)p.x * 64 + lane]), a0);
    }

    float acc = ((a0 + a1) + (a2 + a3)) + ((a4 + a5) + (a6 + a7));
    float o = fmaf(0.5f, yself, fmaf(0.5f, acc, sv));
    Yof[idx] = o;
    Yob[idx] = f32_to_bf16(o);
}

// ---------------------------------------------------------------------------
// Kernel 4: out = relu(Y) @ W2 + b2.  One node per thread, 40 accumulators.
// ---------------------------------------------------------------------------
__global__ __launch_bounds__(256) void mlp2(const float* __restrict__ Y,
                                            const float* __restrict__ W2,
                                            const float* __restrict__ b2,
                                            float* __restrict__ out) {
    __shared__ float W2s[D_HID * D_OUT];  // 10.2 KB
    __shared__ float b2s[D_OUT];
    int tid = threadIdx.x;
    for (int i = tid; i < D_HID * D_OUT; i += 256) W2s[i] = W2[i];
    if (tid < D_OUT) b2s[tid] = b2[tid];
    __syncthreads();

    int n = blockIdx.x * 256 + tid;
    if (n >= N_NODES) return;

    float acc[D_OUT];
    #pragma unroll
    for (int o = 0; o < D_OUT; ++o) acc[o] = b2s[o];

    const float4* Y4 = (const float4*)(Y + (size_t)n * 64);
    #pragma unroll 4
    for (int k4 = 0; k4 < 16; ++k4) {
        float4 y = Y4[k4];
        float ys[4];
        ys[0] = fmaxf(y.x, 0.0f); ys[1] = fmaxf(y.y, 0.0f);
        ys[2] = fmaxf(y.z, 0.0f); ys[3] = fmaxf(y.w, 0.0f);
        #pragma unroll
        for (int j = 0; j < 4; ++j) {
            int k = k4 * 4 + j;
            #pragma unroll
            for (int o = 0; o < D_OUT; ++o)
                acc[o] = fmaf(ys[j], W2s[k * D_OUT + o], acc[o]);
        }
    }

    float4* o4 = (float4*)(out + (size_t)n * D_OUT);  // 160 B row, 16B aligned
    #pragma unroll
    for (int q = 0; q < 10; ++q)
        o4[q] = make_float4(acc[4 * q], acc[4 * q + 1], acc[4 * q + 2], acc[4 * q + 3]);
}

// ---------------------------------------------------------------------------
extern "C" void kernel_launch(void* const* d_in, const int* in_sizes, int n_in,
                              void* d_out, int out_size, void* d_ws, size_t ws_size,
                              hipStream_t stream) {
    const float* x     = (const float*)d_in[0];
    const int*   erow  = (const int*)  d_in[1];
    const int*   ecol  = (const int*)  d_in[2];
    const float* evalv = (const float*)d_in[3];
    const float* diag  = (const float*)d_in[4];
    const float* W1    = (const float*)d_in[5];
    const float* b1    = (const float*)d_in[6];
    const float* W2    = (const float*)d_in[7];
    const float* b2    = (const float*)d_in[8];
    float* out = (float*)d_out;

    // workspace layout (bytes):
    //   Y0f, Y1f, src : 3 x 25.6 MB fp32
    //   Y0b, Y1b      : 2 x 12.8 MB bf16
    //   ep            : 12.8 MB int2
    //   rp            : 0.4 MB
    const size_t NV = (size_t)N_NODES * D_HID;
    float*          Y0f = (float*)d_ws;
    float*          Y1f = Y0f + NV;
    float*          src = Y1f + NV;
    unsigned short* Y0b = (unsigned short*)(src + NV);
    unsigned short* Y1b = Y0b + NV;
    int2*           ep  = (int2*)(Y1b + NV);
    int*            rp  = (int*)(ep + N_EDGES);

    build_rowptr<<<(N_NODES + 1 + 255) / 256, 256, 0, stream>>>(erow, rp);
    pack_edges<<<(N_EDGES + 255) / 256, 256, 0, stream>>>(ecol, evalv, ep);
    mlp1<<<N_NODES / 32, 256, 0, stream>>>(x, W1, b1, diag, Y0f, Y0b, src);

    float*          Yf[2] = {Y0f, Y1f};
    unsigned short* Yb[2] = {Y0b, Y1b};
    for (int i = 0; i < PROP_N; ++i) {
        prop_step<<<(N_NODES + 3) / 4, 256, 0, stream>>>(
            Yf[i & 1], Yb[i & 1], src, Yf[(i + 1) & 1], Yb[(i + 1) & 1], rp, ep);
    }
    // PROP_N even -> final fp32 result in Y0f
    mlp2<<<(N_NODES + 255) / 256, 256, 0, stream>>>(Y0f, W2, b2, out);
}

// Round 4
// 985.492 us; speedup vs baseline: 2.2669x; 1.0389x over previous
//
#include <hip/hip_runtime.h>

#define N_NODES 100000
#define N_EDGES 1600000
#define D_IN    256
#define D_HID   64
#define D_OUT   40
#define PROP_N  16

// ---- fp8 (OCP e4m3) helpers: HW convert, RNE, saturating ------------------
__device__ __forceinline__ float fp8_to_f32(int b) {
    return __builtin_amdgcn_cvt_f32_fp8(b, 0);
}
__device__ __forceinline__ unsigned char f32_to_fp8(float f) {
    int p = __builtin_amdgcn_cvt_pk_fp8_f32(f, f, 0, false);
    return (unsigned char)(p & 0xff);
}
__device__ __forceinline__ unsigned short f32x2_to_fp8x2(float a, float b) {
    int p = __builtin_amdgcn_cvt_pk_fp8_f32(a, b, 0, false);
    return (unsigned short)(p & 0xffff);
}

// ---------------------------------------------------------------------------
// Kernel 1: CSR row_ptr from sorted edge_row via binary search (lower_bound).
// ---------------------------------------------------------------------------
__global__ __launch_bounds__(256) void build_rowptr(const int* __restrict__ erow,
                                                    int* __restrict__ rp) {
    int r = blockIdx.x * blockDim.x + threadIdx.x;
    if (r > N_NODES) return;
    int lo = 0, hi = N_EDGES;
    while (lo < hi) {
        int mid = (lo + hi) >> 1;
        if (erow[mid] < r) lo = mid + 1; else hi = mid;
    }
    rp[r] = lo;
}

// ---------------------------------------------------------------------------
// Kernel 1b: pack (col, val) into int2 so the edge loop does one 8B load/edge.
// ---------------------------------------------------------------------------
__global__ __launch_bounds__(256) void pack_edges(const int* __restrict__ ecol,
                                                  const float* __restrict__ evalv,
                                                  int2* __restrict__ ep) {
    int i = blockIdx.x * blockDim.x + threadIdx.x;
    if (i >= N_EDGES) return;
    ep[i] = make_int2(ecol[i], __float_as_int(evalv[i]));
}

// ---------------------------------------------------------------------------
// Kernel 2: h = x @ W1 + b1 ; Y0f = h ; Y08 = fp8(h) ; src = 0.5 * diag * h
// ---------------------------------------------------------------------------
__global__ __launch_bounds__(256) void mlp1(const float* __restrict__ x,
                                            const float* __restrict__ W1,
                                            const float* __restrict__ b1,
                                            const float* __restrict__ diag,
                                            float* __restrict__ Y0f,
                                            unsigned char* __restrict__ Y08,
                                            float* __restrict__ src) {
    __shared__ float xs[32 * D_IN];  // 32 KB
    const int tid   = threadIdx.x;
    const int nbase = blockIdx.x * 32;

    {
        const float4* xv  = (const float4*)(x + (size_t)nbase * D_IN);
        float4*       xsv = (float4*)xs;
        #pragma unroll
        for (int i = 0; i < 8; ++i)
            xsv[tid + 256 * i] = xv[tid + 256 * i];
    }
    __syncthreads();

    const int dp = (tid & 31) * 2;   // dim pair
    const int ng = tid >> 5;         // node group 0..7 (4 nodes each)

    const float bx = b1[dp], by = b1[dp + 1];
    float a[4][2];
    #pragma unroll
    for (int i = 0; i < 4; ++i) { a[i][0] = bx; a[i][1] = by; }

    const float* xrow = xs + (size_t)(ng * 4) * D_IN;

    for (int k4 = 0; k4 < 64; ++k4) {
        const int k = k4 * 4;
        float2 w0 = *(const float2*)&W1[(k + 0) * 64 + dp];
        float2 w1 = *(const float2*)&W1[(k + 1) * 64 + dp];
        float2 w2 = *(const float2*)&W1[(k + 2) * 64 + dp];
        float2 w3 = *(const float2*)&W1[(k + 3) * 64 + dp];
        #pragma unroll
        for (int i = 0; i < 4; ++i) {
            float4 xq = *(const float4*)&xrow[i * D_IN + k];
            a[i][0] = fmaf(xq.x, w0.x, a[i][0]); a[i][1] = fmaf(xq.x, w0.y, a[i][1]);
            a[i][0] = fmaf(xq.y, w1.x, a[i][0]); a[i][1] = fmaf(xq.y, w1.y, a[i][1]);
            a[i][0] = fmaf(xq.z, w2.x, a[i][0]); a[i][1] = fmaf(xq.z, w2.y, a[i][1]);
            a[i][0] = fmaf(xq.w, w3.x, a[i][0]); a[i][1] = fmaf(xq.w, w3.y, a[i][1]);
        }
    }

    #pragma unroll
    for (int i = 0; i < 4; ++i) {
        const int n = nbase + ng * 4 + i;
        const float dg = diag[n];
        float2 h  = make_float2(a[i][0], a[i][1]);
        float2 sc = make_float2(0.5f * dg * h.x, 0.5f * dg * h.y);
        *(float2*)&Y0f[(size_t)n * 64 + dp] = h;
        *(float2*)&src[(size_t)n * 64 + dp] = sc;
        *(unsigned short*)&Y08[(size_t)n * 64 + dp] = f32x2_to_fp8x2(h.x, h.y);
    }
}

// ---------------------------------------------------------------------------
// Kernel 3: one propagation step. One wave per row, lane = feature dim.
// Gathers read the fp8 copy (64 B/row = 1 cache line); self-term + src stay
// fp32 so quantization only enters via the 0.5*A path (gain ~0.25/step).
// 8-wide unroll: 8 gathers + 8 edge loads in flight per wave.
// ---------------------------------------------------------------------------
__global__ __launch_bounds__(256) void prop_step(const float* __restrict__ Yf,
                                                 const unsigned char* __restrict__ Y8,
                                                 const float* __restrict__ src,
                                                 float* __restrict__ Yof,
                                                 unsigned char* __restrict__ Yo8,
                                                 const int* __restrict__ rp,
                                                 const int2* __restrict__ ep) {
    int w    = blockIdx.x * (blockDim.x >> 6) + (threadIdx.x >> 6);
    int lane = threadIdx.x & 63;
    if (w >= N_NODES) return;

    int e0 = __builtin_amdgcn_readfirstlane(rp[w]);
    int e1 = __builtin_amdgcn_readfirstlane(rp[w + 1]);

    const size_t idx = (size_t)w * 64 + lane;
    float yself = Yf[idx];
    float sv    = src[idx];

    float a0 = 0.f, a1 = 0.f, a2 = 0.f, a3 = 0.f;
    float a4 = 0.f, a5 = 0.f, a6 = 0.f, a7 = 0.f;
    int e = e0;
    for (; e + 8 <= e1; e += 8) {
        int2 p0 = ep[e + 0], p1 = ep[e + 1], p2 = ep[e + 2], p3 = ep[e + 3];
        int2 p4 = ep[e + 4], p5 = ep[e + 5], p6 = ep[e + 6], p7 = ep[e + 7];
        int b0 = Y8[(size_t)p0.x * 64 + lane];
        int b1 = Y8[(size_t)p1.x * 64 + lane];
        int b2 = Y8[(size_t)p2.x * 64 + lane];
        int b3 = Y8[(size_t)p3.x * 64 + lane];
        int b4 = Y8[(size_t)p4.x * 64 + lane];
        int b5 = Y8[(size_t)p5.x * 64 + lane];
        int b6 = Y8[(size_t)p6.x * 64 + lane];
        int b7 = Y8[(size_t)p7.x * 64 + lane];
        a0 = fmaf(__int_as_float(p0.y), fp8_to_f32(b0), a0);
        a1 = fmaf(__int_as_float(p1.y), fp8_to_f32(b1), a1);
        a2 = fmaf(__int_as_float(p2.y), fp8_to_f32(b2), a2);
        a3 = fmaf(__int_as_float(p3.y), fp8_to_f32(b3), a3);
        a4 = fmaf(__int_as_float(p4.y), fp8_to_f32(b4), a4);
        a5 = fmaf(__int_as_float(p5.y), fp8_to_f32(b5), a5);
        a6 = fmaf(__int_as_float(p6.y), fp8_to_f32(b6), a6);
        a7 = fmaf(__int_as_float(p7.y), fp8_to_f32(b7), a7);
    }
    if (e + 4 <= e1) {
        int2 p0 = ep[e + 0], p1 = ep[e + 1], p2 = ep[e + 2], p3 = ep[e + 3];
        int b0 = Y8[(size_t)p0.x * 64 + lane];
        int b1 = Y8[(size_t)p1.x * 64 + lane];
        int b2 = Y8[(size_t)p2.x * 64 + lane];
        int b3 = Y8[(size_t)p3.x * 64 + lane];
        a0 = fmaf(__int_as_float(p0.y), fp8_to_f32(b0), a0);
        a1 = fmaf(__int_as_float(p1.y), fp8_to_f32(b1), a1);
        a2 = fmaf(__int_as_float(p2.y), fp8_to_f32(b2), a2);
        a3 = fmaf(__int_as_float(p3.y), fp8_to_f32(b3), a3);
        e += 4;
    }
    for (; e < e1; ++e) {
        int2 p = ep[e];
        a0 = fmaf(__int_as_float(p.y),
                  fp8_to_f32((int)Y8[(size_t)p.x * 64 + lane]), a0);
    }

    float acc = ((a0 + a1) + (a2 + a3)) + ((a4 + a5) + (a6 + a7));
    float o = fmaf(0.5f, yself, fmaf(0.5f, acc, sv));
    Yof[idx] = o;
    Yo8[idx] = f32_to_fp8(o);
}

// ---------------------------------------------------------------------------
// Kernel 4: out = relu(Y) @ W2 + b2.  One node per thread, 40 accumulators.
// ---------------------------------------------------------------------------
__global__ __launch_bounds__(256) void mlp2(const float* __restrict__ Y,
                                            const float* __restrict__ W2,
                                            const float* __restrict__ b2,
                                            float* __restrict__ out) {
    __shared__ float W2s[D_HID * D_OUT];  // 10.2 KB
    __shared__ float b2s[D_OUT];
    int tid = threadIdx.x;
    for (int i = tid; i < D_HID * D_OUT; i += 256) W2s[i] = W2[i];
    if (tid < D_OUT) b2s[tid] = b2[tid];
    __syncthreads();

    int n = blockIdx.x * 256 + tid;
    if (n >= N_NODES) return;

    float acc[D_OUT];
    #pragma unroll
    for (int o = 0; o < D_OUT; ++o) acc[o] = b2s[o];

    const float4* Y4 = (const float4*)(Y + (size_t)n * 64);
    #pragma unroll 4
    for (int k4 = 0; k4 < 16; ++k4) {
        float4 y = Y4[k4];
        float ys[4];
        ys[0] = fmaxf(y.x, 0.0f); ys[1] = fmaxf(y.y, 0.0f);
        ys[2] = fmaxf(y.z, 0.0f); ys[3] = fmaxf(y.w, 0.0f);
        #pragma unroll
        for (int j = 0; j < 4; ++j) {
            int k = k4 * 4 + j;
            #pragma unroll
            for (int o = 0; o < D_OUT; ++o)
                acc[o] = fmaf(ys[j], W2s[k * D_OUT + o], acc[o]);
        }
    }

    float4* o4 = (float4*)(out + (size_t)n * D_OUT);  // 160 B row, 16B aligned
    #pragma unroll
    for (int q = 0; q < 10; ++q)
        o4[q] = make_float4(acc[4 * q], acc[4 * q + 1], acc[4 * q + 2], acc[4 * q + 3]);
}

// ---------------------------------------------------------------------------
extern "C" void kernel_launch(void* const* d_in, const int* in_sizes, int n_in,
                              void* d_out, int out_size, void* d_ws, size_t ws_size,
                              hipStream_t stream) {
    const float* x     = (const float*)d_in[0];
    const int*   erow  = (const int*)  d_in[1];
    const int*   ecol  = (const int*)  d_in[2];
    const float* evalv = (const float*)d_in[3];
    const float* diag  = (const float*)d_in[4];
    const float* W1    = (const float*)d_in[5];
    const float* b1    = (const float*)d_in[6];
    const float* W2    = (const float*)d_in[7];
    const float* b2    = (const float*)d_in[8];
    float* out = (float*)d_out;

    // workspace layout:
    //   Y0f, Y1f, src : 3 x 25.6 MB fp32
    //   Y08, Y18      : 2 x 6.4 MB fp8
    //   ep            : 12.8 MB int2
    //   rp            : 0.4 MB
    const size_t NV = (size_t)N_NODES * D_HID;
    float*         Y0f = (float*)d_ws;
    float*         Y1f = Y0f + NV;
    float*         src = Y1f + NV;
    unsigned char* Y08 = (unsigned char*)(src + NV);
    unsigned char* Y18 = Y08 + NV;
    int2*          ep  = (int2*)(Y18 + NV);
    int*           rp  = (int*)(ep + N_EDGES);

    build_rowptr<<<(N_NODES + 1 + 255) / 256, 256, 0, stream>>>(erow, rp);
    pack_edges<<<(N_EDGES + 255) / 256, 256, 0, stream>>>(ecol, evalv, ep);
    mlp1<<<N_NODES / 32, 256, 0, stream>>>(x, W1, b1, diag, Y0f, Y08, src);

    float*         Yf[2] = {Y0f, Y1f};
    unsigned char* Y8[2] = {Y08, Y18};
    for (int i = 0; i < PROP_N; ++i) {
        prop_step<<<(N_NODES + 3) / 4, 256, 0, stream>>>(
            Yf[i & 1], Y8[i & 1], src, Yf[(i + 1) & 1], Y8[(i + 1) & 1], rp, ep);
    }
    // PROP_N even -> final fp32 result in Y0f
    mlp2<<<(N_NODES + 255) / 256, 256, 0, stream>>>(Y0f, W2, b2, out);
}